// Round 1
// baseline (257.919 us; speedup 1.0000x reference)
//
#include <hip/hip_runtime.h>
#include <hip/hip_bf16.h>

// PatchConv2d: out[b,o,h,w] = conv3x3(x,kernel) + 0.1*(h+w)*patch_sum[b,h,w] + bias[o]
// x:(16,64,128,128) f32, kernel:(128,64,3,3) f32, bias:(128,) f32 -> out(16,128,128,128) f32
//
// R4: (1) prep_x vectorized: float4 global loads (batched 8-deep/thread),
//     XOR-swizzled f32 LDS tile -> conflict-free b128 writes AND column pack
//     reads; S from register partials. (2) conv_main: 2 output rows/block
//     (4 staged rows, B-frags reused across rows, 576 MFMA/wave/barrier).
//     (3) coherent XCD swizzle across prep_x/conv_main for L2 locality.

typedef __attribute__((ext_vector_type(8))) short short8;
typedef __attribute__((ext_vector_type(4))) float f32x4;

#define B_COEF 0.1f
constexpr int CI = 64, CO = 128, H = 128, W = 128;
constexpr int XPAD = 72;  // LDS row stride (elems): 36 dwords -> conflict-free b128

static __device__ inline short bf16s(float v) {
    __hip_bfloat16 b = __float2bfloat16(v);
    return *reinterpret_cast<short*>(&b);
}

// ============================ fast path ====================================

// x NCHW f32 -> x_t NHWC bf16 ; S[b][h][w] = sum_ci x (fp32)
// f32 tile layout: tile[ci*132 + (w ^ (4*(ci>>3)))] -- float4-aligned swizzle.
//   write: float4 at col 4*((w>>2) ^ (ci>>3))  -> uniform 8 dwords/bank
//   read : scalar col (w ^ 4*(ci>>3))          -> 2 lanes/bank (free)
__global__ __launch_bounds__(256)
void prep_x(const float* __restrict__ x, __hip_bfloat16* __restrict__ xt,
            float* __restrict__ S) {
    __shared__ float tile[64 * 132];
    __shared__ float psum[8 * 128];
    const int bx = blockIdx.x, b = blockIdx.y, tid = threadIdx.x;
    // XCD-coherent remap: xcd = bx&7 owns h in [xcd*16, xcd*16+16)
    const int h = ((bx & 7) << 4) | (bx >> 3);
    const int q = tid & 31, cbase = tid >> 5;

    // ---- batched vector loads: 8 x float4 per thread (rows cbase*8..+7)
    const float* xp = x + (((size_t)b * CI + cbase * 8) * H + h) * W + q * 4;
    f32x4 v[8];
#pragma unroll
    for (int it = 0; it < 8; ++it)
        v[it] = *(const f32x4*)(xp + (size_t)it * H * W);

    const int cw = 4 * (q ^ cbase);  // swizzled col base (float units)
    f32x4 sacc = v[0];
#pragma unroll
    for (int it = 0; it < 8; ++it) {
        *(f32x4*)&tile[(cbase * 8 + it) * 132 + cw] = v[it];
        if (it) sacc += v[it];
    }
    *(f32x4*)&psum[cbase * 128 + 4 * q] = sacc;  // partial channel-sum (8 ci)
    __syncthreads();  // the only barrier

    // ---- S = sum over all 64 ci
    if (tid < 128) {
        float s = 0.0f;
#pragma unroll
        for (int g = 0; g < 8; ++g) s += psum[g * 128 + tid];
        S[((size_t)b * H + h) * W + tid] = s;
    }

    // ---- pack columns -> NHWC bf16 (short8 = 8 ci per store)
    const int c8 = (tid & 7) * 8, wl = tid >> 3, sw = 4 * (tid & 7);
#pragma unroll
    for (int it = 0; it < 4; ++it) {
        int ww = wl + it * 32;
        short8 pk;
#pragma unroll
        for (int j = 0; j < 8; ++j)
            pk[j] = bf16s(tile[(c8 + j) * 132 + (ww ^ sw)]);
        *(short8*)(xt + (((size_t)b * H + h) * W + ww) * CI + c8) = pk;
    }
}

// kernel f32 [oc][ci][3][3] -> bf16 wq[tap][kc][oc][32] (ci = kc*32+j)
__global__ void prep_wq(const float* __restrict__ wgt, __hip_bfloat16* __restrict__ wq) {
    int idx = blockIdx.x * 256 + threadIdx.x;  // 9*128*64 = 73728
    if (idx < 9 * CO * CI) {
        int tap = idx >> 13;
        int rem = idx & 8191;
        int oc = rem >> 6, ci = rem & 63;
        int kc = ci >> 5, j = ci & 31;
        wq[(((tap * 2 + kc) * CO + oc) << 5) + j] =
            __float2bfloat16(wgt[(oc * CI + ci) * 9 + tap]);
    }
}

// 2 output rows per block: stage 4 input rows, reuse B-frags across rows.
__global__ __launch_bounds__(256, 2)
void conv_main(const __hip_bfloat16* __restrict__ xt,
               const __hip_bfloat16* __restrict__ wq,
               const float* __restrict__ S,
               const float* __restrict__ bias,
               float* __restrict__ out) {
    __shared__ __hip_bfloat16 xrow[4][130 * XPAD];  // 74,880 B
    __shared__ float ssum[2][132];

    const int tid = threadIdx.x, bx = blockIdx.x, b = blockIdx.y;
    // XCD-coherent: xcd = bx&7 owns strips [xcd*8, xcd*8+8) = h [xcd*16,+16)
    const int strip = ((bx & 7) << 3) | (bx >> 3);
    const int h0 = strip * 2;
    const int lane = tid & 63, waveid = tid >> 6;
    const int lo16 = lane & 15, quad = lane >> 4;
    const int m0 = (waveid & 1) * 64, n0 = (waveid >> 1) * 64;

    // ---- stage 4 halo rows (vector 16B, zero-padded edges)
    const int c8 = (tid & 7) * 8, wl = tid >> 3;
#pragma unroll
    for (int r = 0; r < 4; ++r) {
        const int gh = h0 - 1 + r;
#pragma unroll
        for (int it = 0; it < 5; ++it) {
            int w = wl + it * 32;
            if (w < 130) {
                int gw = w - 1;
                short8 v = {0, 0, 0, 0, 0, 0, 0, 0};
                if (gh >= 0 && gh < H && gw >= 0 && gw < W)
                    v = *(const short8*)(xt + (((size_t)b * H + gh) * W + gw) * CI + c8);
                *(short8*)&xrow[r][w * XPAD + c8] = v;
            }
        }
    }
    // ---- kh-summed S windows for both output rows
    if (tid < 130) {
        int gw = tid - 1;
        float s4[4] = {0.0f, 0.0f, 0.0f, 0.0f};
        if (gw >= 0 && gw < W) {
#pragma unroll
            for (int r = 0; r < 4; ++r) {
                int gh = h0 - 1 + r;
                if (gh >= 0 && gh < H) s4[r] = S[((size_t)b * H + gh) * W + gw];
            }
        }
        ssum[0][tid] = s4[0] + s4[1] + s4[2];
        ssum[1][tid] = s4[1] + s4[2] + s4[3];
    }
    __syncthreads();  // the only barrier

    f32x4 acc[2][4][4] = {};

#pragma unroll
    for (int kh = 0; kh < 3; ++kh) {
#pragma unroll
        for (int kw = 0; kw < 3; ++kw) {
            const int tap = kh * 3 + kw;
            // B-frags straight from L2-resident wq; reused for both rows
            short8 bq[2][4];
#pragma unroll
            for (int kc = 0; kc < 2; ++kc)
#pragma unroll
                for (int ni = 0; ni < 4; ++ni)
                    bq[kc][ni] = *(const short8*)(
                        wq + (((tap * 2 + kc) * CO + n0 + ni * 16 + lo16) << 5) + quad * 8);
#pragma unroll
            for (int r = 0; r < 2; ++r) {
#pragma unroll
                for (int kc = 0; kc < 2; ++kc) {
                    short8 af[4];
#pragma unroll
                    for (int mi = 0; mi < 4; ++mi)
                        af[mi] = *(const short8*)
                            &xrow[kh + r][(m0 + mi * 16 + lo16 + kw) * XPAD + kc * 32 + quad * 8];
#pragma unroll
                    for (int mi = 0; mi < 4; ++mi)
#pragma unroll
                        for (int ni = 0; ni < 4; ++ni)
                            acc[r][mi][ni] = __builtin_amdgcn_mfma_f32_16x16x32_bf16(
                                af[mi], bq[kc][ni], acc[r][mi][ni], 0, 0, 0);
                }
            }
        }
    }

    // ---- epilogue: + 0.1*(h+w)*patch_sum + bias; float4 stores, both rows
#pragma unroll
    for (int r = 0; r < 2; ++r) {
        const int h = h0 + r;
#pragma unroll
        for (int mi = 0; mi < 4; ++mi) {
            const int wbase = m0 + mi * 16 + quad * 4;
            float cs[6];
#pragma unroll
            for (int t = 0; t < 6; ++t) cs[t] = ssum[r][wbase + t];
            float ps[4], cf[4];
#pragma unroll
            for (int t = 0; t < 4; ++t) {
                ps[t] = cs[t] + cs[t + 1] + cs[t + 2];
                cf[t] = B_COEF * (float)(h + wbase + t);
            }
#pragma unroll
            for (int ni = 0; ni < 4; ++ni) {
                const int oc = n0 + ni * 16 + lo16;
                const float bv = bias[oc];
                f32x4 vv = acc[r][mi][ni];
#pragma unroll
                for (int t = 0; t < 4; ++t) vv[t] = vv[t] + cf[t] * ps[t] + bv;
                *(f32x4*)(out + (((size_t)b * CO + oc) * H + h) * W + wbase) = vv;
            }
        }
    }
}

// ===================== fallback path (R2, needs only 147 KB ws) ============

constexpr int WPAD = 72;

__global__ void prep_w_fb(const float* __restrict__ wgt, __hip_bfloat16* __restrict__ wt) {
    int idx = blockIdx.x * 256 + threadIdx.x;
    if (idx < 9 * CO * CI) {
        int tap = idx / (CO * CI);
        int rem = idx - tap * (CO * CI);
        int oc = rem >> 6, ci = rem & 63;
        wt[idx] = __float2bfloat16(wgt[(oc * CI + ci) * 9 + tap]);
    }
}

__global__ __launch_bounds__(256, 2)
void conv_fb(const float* __restrict__ x, const __hip_bfloat16* __restrict__ wt,
             const float* __restrict__ bias, float* __restrict__ out) {
    __shared__ __hip_bfloat16 xrow[130 * XPAD];
    __shared__ __hip_bfloat16 wlds[CO * WPAD];
    __shared__ float colsum[132];

    const int tid = threadIdx.x;
    const int h = blockIdx.x, b = blockIdx.y;
    const int lane = tid & 63, waveid = tid >> 6;
    const int lo16 = lane & 15, quad = lane >> 4;
    const int m0 = (waveid & 1) * 64, n0 = (waveid >> 1) * 64;

    f32x4 acc[4][4] = {};
    if (tid < 132) colsum[tid] = 0.0f;
    const float* xb = x + (size_t)b * CI * H * W;

    const int w16 = tid & 15, cipl = (tid >> 4) & 3, rest0 = tid >> 6;

    for (int kh = 0; kh < 3; ++kh) {
        const int gh = h - 1 + kh;
        __syncthreads();
        for (int it = 0; it < 18; ++it) {
            int rest = rest0 + it * 4;
            int whi = rest % 9, ciph = rest / 9;
            int w = whi * 16 + w16;
            int ci0 = (ciph * 4 + cipl) * 2;
            int gw = w - 1;
            float x0 = 0.0f, x1 = 0.0f;
            if (w < 130 && gw >= 0 && gw < W && gh >= 0 && gh < H) {
                const float* p = xb + (size_t)ci0 * (H * W) + gh * W + gw;
                x0 = p[0];
                x1 = p[H * W];
            }
            if (w < 130) {
                __hip_bfloat162 pk;
                pk.x = __float2bfloat16(x0);
                pk.y = __float2bfloat16(x1);
                *(__hip_bfloat162*)&xrow[w * XPAD + ci0] = pk;
            }
            float cs = x0 + x1;
            cs += __shfl_xor(cs, 16);
            cs += __shfl_xor(cs, 32);
            if (quad == 0 && w < 130) atomicAdd(&colsum[w], cs);
        }
        for (int kw = 0; kw < 3; ++kw) {
            __syncthreads();
            {
                const __hip_bfloat16* wtap = wt + (kh * 3 + kw) * (CO * CI);
#pragma unroll
                for (int it = 0; it < 4; ++it) {
                    int j = tid + it * 256;
                    int oc = j >> 3, ch = (j & 7) * 8;
                    short8 v = *(const short8*)(wtap + oc * CI + ch);
                    *(short8*)&wlds[oc * WPAD + ch] = v;
                }
            }
            __syncthreads();
#pragma unroll
            for (int kc = 0; kc < 2; ++kc) {
                const int krow = kc * 32 + quad * 8;
                short8 af[4], bf[4];
#pragma unroll
                for (int mi = 0; mi < 4; ++mi)
                    af[mi] = *(const short8*)&xrow[(m0 + mi * 16 + lo16 + kw) * XPAD + krow];
#pragma unroll
                for (int ni = 0; ni < 4; ++ni)
                    bf[ni] = *(const short8*)&wlds[(n0 + ni * 16 + lo16) * WPAD + krow];
#pragma unroll
                for (int mi = 0; mi < 4; ++mi)
#pragma unroll
                    for (int ni = 0; ni < 4; ++ni)
                        acc[mi][ni] = __builtin_amdgcn_mfma_f32_16x16x32_bf16(
                            af[mi], bf[ni], acc[mi][ni], 0, 0, 0);
            }
        }
    }
    __syncthreads();
#pragma unroll
    for (int mi = 0; mi < 4; ++mi) {
        const int wbase = m0 + mi * 16 + quad * 4;
        float cs[6];
#pragma unroll
        for (int r = 0; r < 6; ++r) cs[r] = colsum[wbase + r];
        float ps[4], cf[4];
#pragma unroll
        for (int r = 0; r < 4; ++r) {
            ps[r] = cs[r] + cs[r + 1] + cs[r + 2];
            cf[r] = B_COEF * (float)(h + wbase + r);
        }
#pragma unroll
        for (int ni = 0; ni < 4; ++ni) {
            const int oc = n0 + ni * 16 + lo16;
            const float bv = bias[oc];
            f32x4 v = acc[mi][ni];
#pragma unroll
            for (int r = 0; r < 4; ++r) v[r] = v[r] + cf[r] * ps[r] + bv;
            *(f32x4*)(out + (((size_t)b * CO + oc) * H + h) * W + wbase) = v;
        }
    }
}

// ===========================================================================

extern "C" void kernel_launch(void* const* d_in, const int* in_sizes, int n_in,
                              void* d_out, int out_size, void* d_ws, size_t ws_size,
                              hipStream_t stream) {
    const float* x    = (const float*)d_in[0];
    const float* wgt  = (const float*)d_in[1];
    const float* bias = (const float*)d_in[2];
    float* out = (float*)d_out;

    const size_t XT_BYTES = (size_t)16 * H * W * CI * 2;          // 33,554,432
    const size_t S_BYTES  = (size_t)16 * H * W * 4;               //  1,048,576
    const size_t WQ_BYTES = (size_t)9 * 2 * CO * 32 * 2;          //    147,456

    if (ws_size >= XT_BYTES + S_BYTES + WQ_BYTES) {
        __hip_bfloat16* xt = (__hip_bfloat16*)d_ws;
        float* S           = (float*)((char*)d_ws + XT_BYTES);
        __hip_bfloat16* wq = (__hip_bfloat16*)((char*)d_ws + XT_BYTES + S_BYTES);
        prep_x<<<dim3(H, 16), dim3(256), 0, stream>>>(x, xt, S);
        prep_wq<<<dim3(288), dim3(256), 0, stream>>>(wgt, wq);
        conv_main<<<dim3(H / 2, 16), dim3(256), 0, stream>>>(xt, wq, S, bias, out);
    } else {
        __hip_bfloat16* wt = (__hip_bfloat16*)d_ws;  // 147,456 B
        prep_w_fb<<<dim3(288), dim3(256), 0, stream>>>(wgt, wt);
        conv_fb<<<dim3(H, 16), dim3(256), 0, stream>>>(x, wt, bias, out);
    }
}

// Round 2
// 238.869 us; speedup vs baseline: 1.0797x; 1.0797x over previous
//
#include <hip/hip_runtime.h>
#include <hip/hip_bf16.h>

// PatchConv2d: out[b,o,h,w] = conv3x3(x,kernel) + 0.1*(h+w)*patch_sum[b,h,w] + bias[o]
// x:(16,64,128,128) f32, kernel:(128,64,3,3) f32, bias:(128,) f32 -> out(16,128,128,128) f32
//
// R5: conv_main W-split for occupancy: each block = 1 output row x 64 w.
//     LDS tile 3x66x64ci = 28.5 KB -> 4 blocks/CU (vs 2), one barrier.
//     Wave layout 1x4 (wave owns 32 oc, full M=64): acc[4][2] = 32 VGPR,
//     __launch_bounds__(256,4) keeps VGPR <= 128 (no spill).
//     prep_x stays R4 (batched float4 loads + conflict-free XOR swizzle).
//     XCD strip remap coherent across prep_x / conv_main.

typedef __attribute__((ext_vector_type(8))) short short8;
typedef __attribute__((ext_vector_type(4))) float f32x4;

#define B_COEF 0.1f
constexpr int CI = 64, CO = 128, H = 128, W = 128;
constexpr int XPAD = 72;  // LDS row stride (elems): 36 dwords -> conflict-free b128

static __device__ inline short bf16s(float v) {
    __hip_bfloat16 b = __float2bfloat16(v);
    return *reinterpret_cast<short*>(&b);
}

// ============================ fast path ====================================

// x NCHW f32 -> x_t NHWC bf16 ; S[b][h][w] = sum_ci x (fp32)
// f32 tile layout: tile[ci*132 + (w ^ (4*(ci>>3)))] -- float4-aligned swizzle.
__global__ __launch_bounds__(256)
void prep_x(const float* __restrict__ x, __hip_bfloat16* __restrict__ xt,
            float* __restrict__ S) {
    __shared__ float tile[64 * 132];
    __shared__ float psum[8 * 128];
    const int bx = blockIdx.x, b = blockIdx.y, tid = threadIdx.x;
    // XCD-coherent remap: xcd = bx&7 owns h in [xcd*16, xcd*16+16)
    const int h = ((bx & 7) << 4) | (bx >> 3);
    const int q = tid & 31, cbase = tid >> 5;

    // ---- batched vector loads: 8 x float4 per thread (rows cbase*8..+7)
    const float* xp = x + (((size_t)b * CI + cbase * 8) * H + h) * W + q * 4;
    f32x4 v[8];
#pragma unroll
    for (int it = 0; it < 8; ++it)
        v[it] = *(const f32x4*)(xp + (size_t)it * H * W);

    const int cw = 4 * (q ^ cbase);  // swizzled col base (float units)
    f32x4 sacc = v[0];
#pragma unroll
    for (int it = 0; it < 8; ++it) {
        *(f32x4*)&tile[(cbase * 8 + it) * 132 + cw] = v[it];
        if (it) sacc += v[it];
    }
    *(f32x4*)&psum[cbase * 128 + 4 * q] = sacc;  // partial channel-sum (8 ci)
    __syncthreads();  // the only barrier

    // ---- S = sum over all 64 ci
    if (tid < 128) {
        float s = 0.0f;
#pragma unroll
        for (int g = 0; g < 8; ++g) s += psum[g * 128 + tid];
        S[((size_t)b * H + h) * W + tid] = s;
    }

    // ---- pack columns -> NHWC bf16 (short8 = 8 ci per store)
    const int c8 = (tid & 7) * 8, wl = tid >> 3, sw = 4 * (tid & 7);
#pragma unroll
    for (int it = 0; it < 4; ++it) {
        int ww = wl + it * 32;
        short8 pk;
#pragma unroll
        for (int j = 0; j < 8; ++j)
            pk[j] = bf16s(tile[(c8 + j) * 132 + (ww ^ sw)]);
        *(short8*)(xt + (((size_t)b * H + h) * W + ww) * CI + c8) = pk;
    }
}

// kernel f32 [oc][ci][3][3] -> bf16 wq[tap][kc][oc][32] (ci = kc*32+j)
__global__ void prep_wq(const float* __restrict__ wgt, __hip_bfloat16* __restrict__ wq) {
    int idx = blockIdx.x * 256 + threadIdx.x;  // 9*128*64 = 73728
    if (idx < 9 * CO * CI) {
        int tap = idx >> 13;
        int rem = idx & 8191;
        int oc = rem >> 6, ci = rem & 63;
        int kc = ci >> 5, j = ci & 31;
        wq[(((tap * 2 + kc) * CO + oc) << 5) + j] =
            __float2bfloat16(wgt[(oc * CI + ci) * 9 + tap]);
    }
}

// One output row x 64-w half per block. LDS 28.5 KB -> 4 blocks/CU.
__global__ __launch_bounds__(256, 4)
void conv_main(const __hip_bfloat16* __restrict__ xt,
               const __hip_bfloat16* __restrict__ wq,
               const float* __restrict__ S,
               const float* __restrict__ bias,
               float* __restrict__ out) {
    __shared__ __hip_bfloat16 xrow[3][66 * XPAD];  // 28,512 B
    __shared__ float ssum[68];

    const int tid = threadIdx.x, bx = blockIdx.x, b = blockIdx.y;
    // XCD-coherent: u bijective in [0,256); xcd = bx&7 owns h in [16*xcd, +16)
    const int u = ((bx & 7) << 5) | (bx >> 3);
    const int h = u >> 1, w0 = (u & 1) * 64;
    const int lane = tid & 63, waveid = tid >> 6;
    const int lo16 = lane & 15, quad = lane >> 4;
    const int n0 = waveid * 32;  // each wave owns 32 oc, full 64-w M-dim

    // ---- stage 3 halo rows x 66 w (vector 16B, zero-padded edges)
    const int c8 = (tid & 7) * 8, wl = tid >> 3;
#pragma unroll
    for (int r = 0; r < 3; ++r) {
        const int gh = h - 1 + r;
#pragma unroll
        for (int it = 0; it < 3; ++it) {
            int w = wl + it * 32;
            if (w < 66) {
                int gw = w0 + w - 1;
                short8 v = {0, 0, 0, 0, 0, 0, 0, 0};
                if (gh >= 0 && gh < H && gw >= 0 && gw < W)
                    v = *(const short8*)(xt + (((size_t)b * H + gh) * W + gw) * CI + c8);
                *(short8*)&xrow[r][w * XPAD + c8] = v;
            }
        }
    }
    // ---- kh-summed S window (patch_sum precursor)
    if (tid < 66) {
        int gw = w0 + tid - 1;
        float s = 0.0f;
        if (gw >= 0 && gw < W) {
#pragma unroll
            for (int r = 0; r < 3; ++r) {
                int gh = h - 1 + r;
                if (gh >= 0 && gh < H) s += S[((size_t)b * H + gh) * W + gw];
            }
        }
        ssum[tid] = s;
    }
    __syncthreads();  // the only barrier

    f32x4 acc[4][2] = {};

#pragma unroll
    for (int kh = 0; kh < 3; ++kh) {
#pragma unroll
        for (int kw = 0; kw < 3; ++kw) {
            const int tap = kh * 3 + kw;
            // B-frags straight from L2-resident wq
            short8 bq[2][2];
#pragma unroll
            for (int kc = 0; kc < 2; ++kc)
#pragma unroll
                for (int ni = 0; ni < 2; ++ni)
                    bq[kc][ni] = *(const short8*)(
                        wq + (((tap * 2 + kc) * CO + n0 + ni * 16 + lo16) << 5) + quad * 8);
#pragma unroll
            for (int kc = 0; kc < 2; ++kc) {
                short8 af[4];
#pragma unroll
                for (int mi = 0; mi < 4; ++mi)
                    af[mi] = *(const short8*)
                        &xrow[kh][(mi * 16 + lo16 + kw) * XPAD + kc * 32 + quad * 8];
#pragma unroll
                for (int mi = 0; mi < 4; ++mi)
#pragma unroll
                    for (int ni = 0; ni < 2; ++ni)
                        acc[mi][ni] = __builtin_amdgcn_mfma_f32_16x16x32_bf16(
                            af[mi], bq[kc][ni], acc[mi][ni], 0, 0, 0);
            }
        }
    }

    // ---- epilogue: + 0.1*(h+w)*patch_sum + bias; float4 stores
#pragma unroll
    for (int mi = 0; mi < 4; ++mi) {
        const int wbase = mi * 16 + quad * 4;  // local w
        float cs[6];
#pragma unroll
        for (int t = 0; t < 6; ++t) cs[t] = ssum[wbase + t];
        float ps[4], cf[4];
#pragma unroll
        for (int t = 0; t < 4; ++t) {
            ps[t] = cs[t] + cs[t + 1] + cs[t + 2];
            cf[t] = B_COEF * (float)(h + w0 + wbase + t);
        }
#pragma unroll
        for (int ni = 0; ni < 2; ++ni) {
            const int oc = n0 + ni * 16 + lo16;
            const float bv = bias[oc];
            f32x4 v = acc[mi][ni];
#pragma unroll
            for (int t = 0; t < 4; ++t) v[t] = v[t] + cf[t] * ps[t] + bv;
            *(f32x4*)(out + (((size_t)b * CO + oc) * H + h) * W + w0 + wbase) = v;
        }
    }
}

// ===================== fallback path (R2, needs only 147 KB ws) ============

constexpr int WPAD = 72;

__global__ void prep_w_fb(const float* __restrict__ wgt, __hip_bfloat16* __restrict__ wt) {
    int idx = blockIdx.x * 256 + threadIdx.x;
    if (idx < 9 * CO * CI) {
        int tap = idx / (CO * CI);
        int rem = idx - tap * (CO * CI);
        int oc = rem >> 6, ci = rem & 63;
        wt[idx] = __float2bfloat16(wgt[(oc * CI + ci) * 9 + tap]);
    }
}

__global__ __launch_bounds__(256, 2)
void conv_fb(const float* __restrict__ x, const __hip_bfloat16* __restrict__ wt,
             const float* __restrict__ bias, float* __restrict__ out) {
    __shared__ __hip_bfloat16 xrow[130 * XPAD];
    __shared__ __hip_bfloat16 wlds[CO * WPAD];
    __shared__ float colsum[132];

    const int tid = threadIdx.x;
    const int h = blockIdx.x, b = blockIdx.y;
    const int lane = tid & 63, waveid = tid >> 6;
    const int lo16 = lane & 15, quad = lane >> 4;
    const int m0 = (waveid & 1) * 64, n0 = (waveid >> 1) * 64;

    f32x4 acc[4][4] = {};
    if (tid < 132) colsum[tid] = 0.0f;
    const float* xb = x + (size_t)b * CI * H * W;

    const int w16 = tid & 15, cipl = (tid >> 4) & 3, rest0 = tid >> 6;

    for (int kh = 0; kh < 3; ++kh) {
        const int gh = h - 1 + kh;
        __syncthreads();
        for (int it = 0; it < 18; ++it) {
            int rest = rest0 + it * 4;
            int whi = rest % 9, ciph = rest / 9;
            int w = whi * 16 + w16;
            int ci0 = (ciph * 4 + cipl) * 2;
            int gw = w - 1;
            float x0 = 0.0f, x1 = 0.0f;
            if (w < 130 && gw >= 0 && gw < W && gh >= 0 && gh < H) {
                const float* p = xb + (size_t)ci0 * (H * W) + gh * W + gw;
                x0 = p[0];
                x1 = p[H * W];
            }
            if (w < 130) {
                __hip_bfloat162 pk;
                pk.x = __float2bfloat16(x0);
                pk.y = __float2bfloat16(x1);
                *(__hip_bfloat162*)&xrow[w * XPAD + ci0] = pk;
            }
            float cs = x0 + x1;
            cs += __shfl_xor(cs, 16);
            cs += __shfl_xor(cs, 32);
            if (quad == 0 && w < 130) atomicAdd(&colsum[w], cs);
        }
        for (int kw = 0; kw < 3; ++kw) {
            __syncthreads();
            {
                const __hip_bfloat16* wtap = wt + (kh * 3 + kw) * (CO * CI);
#pragma unroll
                for (int it = 0; it < 4; ++it) {
                    int j = tid + it * 256;
                    int oc = j >> 3, ch = (j & 7) * 8;
                    short8 v = *(const short8*)(wtap + oc * CI + ch);
                    *(short8*)&wlds[oc * WPAD + ch] = v;
                }
            }
            __syncthreads();
#pragma unroll
            for (int kc = 0; kc < 2; ++kc) {
                const int krow = kc * 32 + quad * 8;
                short8 af[4], bf[4];
#pragma unroll
                for (int mi = 0; mi < 4; ++mi)
                    af[mi] = *(const short8*)&xrow[(m0 + mi * 16 + lo16 + kw) * XPAD + krow];
#pragma unroll
                for (int ni = 0; ni < 4; ++ni)
                    bf[ni] = *(const short8*)&wlds[(n0 + ni * 16 + lo16) * WPAD + krow];
#pragma unroll
                for (int mi = 0; mi < 4; ++mi)
#pragma unroll
                    for (int ni = 0; ni < 4; ++ni)
                        acc[mi][ni] = __builtin_amdgcn_mfma_f32_16x16x32_bf16(
                            af[mi], bf[ni], acc[mi][ni], 0, 0, 0);
            }
        }
    }
    __syncthreads();
#pragma unroll
    for (int mi = 0; mi < 4; ++mi) {
        const int wbase = m0 + mi * 16 + quad * 4;
        float cs[6];
#pragma unroll
        for (int r = 0; r < 6; ++r) cs[r] = colsum[wbase + r];
        float ps[4], cf[4];
#pragma unroll
        for (int r = 0; r < 4; ++r) {
            ps[r] = cs[r] + cs[r + 1] + cs[r + 2];
            cf[r] = B_COEF * (float)(h + wbase + r);
        }
#pragma unroll
        for (int ni = 0; ni < 4; ++ni) {
            const int oc = n0 + ni * 16 + lo16;
            const float bv = bias[oc];
            f32x4 v = acc[mi][ni];
#pragma unroll
            for (int r = 0; r < 4; ++r) v[r] = v[r] + cf[r] * ps[r] + bv;
            *(f32x4*)(out + (((size_t)b * CO + oc) * H + h) * W + wbase) = v;
        }
    }
}

// ===========================================================================

extern "C" void kernel_launch(void* const* d_in, const int* in_sizes, int n_in,
                              void* d_out, int out_size, void* d_ws, size_t ws_size,
                              hipStream_t stream) {
    const float* x    = (const float*)d_in[0];
    const float* wgt  = (const float*)d_in[1];
    const float* bias = (const float*)d_in[2];
    float* out = (float*)d_out;

    const size_t XT_BYTES = (size_t)16 * H * W * CI * 2;          // 33,554,432
    const size_t S_BYTES  = (size_t)16 * H * W * 4;               //  1,048,576
    const size_t WQ_BYTES = (size_t)9 * 2 * CO * 32 * 2;          //    147,456

    if (ws_size >= XT_BYTES + S_BYTES + WQ_BYTES) {
        __hip_bfloat16* xt = (__hip_bfloat16*)d_ws;
        float* S           = (float*)((char*)d_ws + XT_BYTES);
        __hip_bfloat16* wq = (__hip_bfloat16*)((char*)d_ws + XT_BYTES + S_BYTES);
        prep_x<<<dim3(H, 16), dim3(256), 0, stream>>>(x, xt, S);
        prep_wq<<<dim3(288), dim3(256), 0, stream>>>(wgt, wq);
        conv_main<<<dim3(2 * H, 16), dim3(256), 0, stream>>>(xt, wq, S, bias, out);
    } else {
        __hip_bfloat16* wt = (__hip_bfloat16*)d_ws;  // 147,456 B
        prep_w_fb<<<dim3(288), dim3(256), 0, stream>>>(wgt, wt);
        conv_fb<<<dim3(H, 16), dim3(256), 0, stream>>>(x, wt, bias, out);
    }
}

// Round 3
// 231.144 us; speedup vs baseline: 1.1158x; 1.0334x over previous
//
#include <hip/hip_runtime.h>
#include <hip/hip_bf16.h>

// PatchConv2d: out[b,o,h,w] = conv3x3(x,kernel) + 0.1*(h+w)*patch_sum[b,h,w] + bias[o]
// x:(16,64,128,128) f32, kernel:(128,64,3,3) f32, bias:(128,) f32 -> out(16,128,128,128) f32
//
// R6: conv_main staging via global_load_lds dwordx4 (27 DMA chunks, zero-page
//     for halo/OOB lanes, pre-swizzled per-lane SOURCE addresses so the LDS
//     stays linear while fragment reads use XOR bank-swizzle s = u ^ (w&7)).
//     s_setprio(1) around the MFMA section (independently-phased blocks).
//     prep_wq + zero-page folded into prep_x (one fewer launch).
//     Occupancy: LDS 27.9 KB, __launch_bounds__(256,4) -> 4 blocks/CU.

typedef __attribute__((ext_vector_type(8))) short short8;
typedef __attribute__((ext_vector_type(4))) float f32x4;

#define B_COEF 0.1f
constexpr int CI = 64, CO = 128, H = 128, W = 128;
constexpr int XPAD = 72;  // fallback-path LDS stride

static __device__ inline short bf16s(float v) {
    __hip_bfloat16 b = __float2bfloat16(v);
    return *reinterpret_cast<short*>(&b);
}

static __device__ inline void gload16(const void* g, const void* l) {
    __builtin_amdgcn_global_load_lds(
        (const __attribute__((address_space(1))) void*)g,
        (__attribute__((address_space(3))) void*)l, 16, 0, 0);
}

// ============================ fast path ====================================

// bx<128: x NCHW f32 -> xt NHWC bf16 ; S[b][h][w] = sum_ci x (fp32)
// bx>=128: kernel f32 [oc][ci][3][3] -> bf16 wq[tap][kc][oc][32] + 16B zero page
__global__ __launch_bounds__(256)
void prep_x(const float* __restrict__ x, const float* __restrict__ wgt,
            __hip_bfloat16* __restrict__ xt, float* __restrict__ S,
            __hip_bfloat16* __restrict__ wq) {
    __shared__ float tile[64 * 132];
    __shared__ float psum[8 * 128];
    const int bx = blockIdx.x, b = blockIdx.y, tid = threadIdx.x;

    if (bx >= H) {  // ---- weight repack + zero page (32 blocks x 256 = 8192 thr)
        int t = ((bx - H) * 16 + b) * 256 + tid;  // 0..8191 = oc*64+ci
        int oc = t >> 6, ci = t & 63;
        int kc = ci >> 5, j = ci & 31;
#pragma unroll
        for (int tap = 0; tap < 9; ++tap)
            wq[(((tap * 2 + kc) * CO + oc) << 5) + j] =
                __float2bfloat16(wgt[(oc * CI + ci) * 9 + tap]);
        if (t == 0) {
            short8 z = {0, 0, 0, 0, 0, 0, 0, 0};
            *(short8*)(wq + 9 * 2 * CO * 32) = z;  // zero page
        }
        return;
    }

    // XCD-coherent remap: xcd = bx&7 owns h in [xcd*16, xcd*16+16)
    const int h = ((bx & 7) << 4) | (bx >> 3);
    const int q = tid & 31, cbase = tid >> 5;

    // ---- batched vector loads: 8 x float4 per thread (rows cbase*8..+7)
    const float* xp = x + (((size_t)b * CI + cbase * 8) * H + h) * W + q * 4;
    f32x4 v[8];
#pragma unroll
    for (int it = 0; it < 8; ++it)
        v[it] = *(const f32x4*)(xp + (size_t)it * H * W);

    const int cw = 4 * (q ^ cbase);  // swizzled col base (float units)
    f32x4 sacc = v[0];
#pragma unroll
    for (int it = 0; it < 8; ++it) {
        *(f32x4*)&tile[(cbase * 8 + it) * 132 + cw] = v[it];
        if (it) sacc += v[it];
    }
    *(f32x4*)&psum[cbase * 128 + 4 * q] = sacc;  // partial channel-sum (8 ci)
    __syncthreads();  // the only barrier

    // ---- S = sum over all 64 ci
    if (tid < 128) {
        float s = 0.0f;
#pragma unroll
        for (int g = 0; g < 8; ++g) s += psum[g * 128 + tid];
        S[((size_t)b * H + h) * W + tid] = s;
    }

    // ---- pack columns -> NHWC bf16 (short8 = 8 ci per store)
    const int c8 = (tid & 7) * 8, wl = tid >> 3, sw = 4 * (tid & 7);
#pragma unroll
    for (int it = 0; it < 4; ++it) {
        int ww = wl + it * 32;
        short8 pk;
#pragma unroll
        for (int j = 0; j < 8; ++j)
            pk[j] = bf16s(tile[(c8 + j) * 132 + (ww ^ sw)]);
        *(short8*)(xt + (((size_t)b * H + h) * W + ww) * CI + c8) = pk;
    }
}

// One output row x 64-w half per block; DMA staging + swizzled reads.
__global__ __launch_bounds__(256, 4)
void conv_main(const __hip_bfloat16* __restrict__ xt,
               const __hip_bfloat16* __restrict__ wq,
               const float* __restrict__ S,
               const float* __restrict__ bias,
               float* __restrict__ out) {
    __shared__ __hip_bfloat16 xrow[3][72 * 64];  // linear rows, 128 B/w
    __shared__ float ssum[68];

    const int tid = threadIdx.x, bx = blockIdx.x, b = blockIdx.y;
    // XCD-coherent: u bijective in [0,256); xcd = bx&7 owns h in [16*xcd,+16)
    const int u = ((bx & 7) << 5) | (bx >> 3);
    const int h = u >> 1, w0 = (u & 1) * 64;
    const int lane = tid & 63, waveid = tid >> 6;
    const int lo16 = lane & 15, quad = lane >> 4;
    const int n0 = waveid * 32;  // wave owns 32 oc, full 64-w M-dim

    const __hip_bfloat16* zpage = wq + 9 * 2 * CO * 32;

    // ---- DMA staging: 27 chunks (3 rows x 9 chunks of 8 w), lane-linear LDS,
    //      swizzle baked into per-lane SOURCE address: slot s = u ^ (w&7).
    const int wl = lane >> 3;                // w within chunk (0..7)
    const int ul = (lane & 7) ^ wl;          // source ci-unit for this lane
    const int lane_elem = wl * 64 + ul * 8;  // element offset within chunk
    for (int idx = waveid; idx < 27; idx += 4) {
        const int r = idx / 9, seg = idx - r * 9;
        const int wb = seg * 8;
        const int gh = h - 1 + r;
        const int wlds = wb + wl;            // 0..71
        const int gw = w0 + wlds - 1;
        const bool valid =
            (gh >= 0) && (gh < H) && (gw >= 0) && (gw < W) && (wlds < 66);
        const void* src = valid
            ? (const void*)(xt + (((size_t)b * H + gh) * W + w0 + wb - 1) * CI + lane_elem)
            : (const void*)zpage;
        gload16(src, &xrow[r][wb * 64]);
    }

    // ---- kh-summed S window (patch_sum precursor)
    if (tid < 66) {
        int gw = w0 + tid - 1;
        float s = 0.0f;
        if (gw >= 0 && gw < W) {
#pragma unroll
            for (int r = 0; r < 3; ++r) {
                int gh = h - 1 + r;
                if (gh >= 0 && gh < H) s += S[((size_t)b * H + gh) * W + gw];
            }
        }
        ssum[tid] = s;
    }
    __syncthreads();  // the only barrier (drains vmcnt for the DMA)

    f32x4 acc[4][2] = {};

    __builtin_amdgcn_s_setprio(1);
#pragma unroll
    for (int kh = 0; kh < 3; ++kh) {
#pragma unroll
        for (int kw = 0; kw < 3; ++kw) {
            const int tap = kh * 3 + kw;
            // B-frags straight from L2-resident wq
            short8 bq[2][2];
#pragma unroll
            for (int kc = 0; kc < 2; ++kc)
#pragma unroll
                for (int ni = 0; ni < 2; ++ni)
                    bq[kc][ni] = *(const short8*)(
                        wq + (((tap * 2 + kc) * CO + n0 + ni * 16 + lo16) << 5) + quad * 8);
#pragma unroll
            for (int kc = 0; kc < 2; ++kc) {
                short8 af[4];
#pragma unroll
                for (int mi = 0; mi < 4; ++mi) {
                    const int row = mi * 16 + lo16 + kw;
                    af[mi] = *(const short8*)
                        &xrow[kh][row * 64 + (((kc * 4 + quad) ^ (row & 7)) * 8)];
                }
#pragma unroll
                for (int mi = 0; mi < 4; ++mi)
#pragma unroll
                    for (int ni = 0; ni < 2; ++ni)
                        acc[mi][ni] = __builtin_amdgcn_mfma_f32_16x16x32_bf16(
                            af[mi], bq[kc][ni], acc[mi][ni], 0, 0, 0);
            }
        }
    }
    __builtin_amdgcn_s_setprio(0);

    // ---- epilogue: + 0.1*(h+w)*patch_sum + bias; float4 stores
#pragma unroll
    for (int mi = 0; mi < 4; ++mi) {
        const int wbase = mi * 16 + quad * 4;  // local w
        float cs[6];
#pragma unroll
        for (int t = 0; t < 6; ++t) cs[t] = ssum[wbase + t];
        float ps[4], cf[4];
#pragma unroll
        for (int t = 0; t < 4; ++t) {
            ps[t] = cs[t] + cs[t + 1] + cs[t + 2];
            cf[t] = B_COEF * (float)(h + w0 + wbase + t);
        }
#pragma unroll
        for (int ni = 0; ni < 2; ++ni) {
            const int oc = n0 + ni * 16 + lo16;
            const float bv = bias[oc];
            f32x4 v = acc[mi][ni];
#pragma unroll
            for (int t = 0; t < 4; ++t) v[t] = v[t] + cf[t] * ps[t] + bv;
            *(f32x4*)(out + (((size_t)b * CO + oc) * H + h) * W + w0 + wbase) = v;
        }
    }
}

// ===================== fallback path (R2, needs only 147 KB ws) ============

constexpr int WPAD = 72;

__global__ void prep_w_fb(const float* __restrict__ wgt, __hip_bfloat16* __restrict__ wt) {
    int idx = blockIdx.x * 256 + threadIdx.x;
    if (idx < 9 * CO * CI) {
        int tap = idx / (CO * CI);
        int rem = idx - tap * (CO * CI);
        int oc = rem >> 6, ci = rem & 63;
        wt[idx] = __float2bfloat16(wgt[(oc * CI + ci) * 9 + tap]);
    }
}

__global__ __launch_bounds__(256, 2)
void conv_fb(const float* __restrict__ x, const __hip_bfloat16* __restrict__ wt,
             const float* __restrict__ bias, float* __restrict__ out) {
    __shared__ __hip_bfloat16 xrow[130 * XPAD];
    __shared__ __hip_bfloat16 wlds[CO * WPAD];
    __shared__ float colsum[132];

    const int tid = threadIdx.x;
    const int h = blockIdx.x, b = blockIdx.y;
    const int lane = tid & 63, waveid = tid >> 6;
    const int lo16 = lane & 15, quad = lane >> 4;
    const int m0 = (waveid & 1) * 64, n0 = (waveid >> 1) * 64;

    f32x4 acc[4][4] = {};
    if (tid < 132) colsum[tid] = 0.0f;
    const float* xb = x + (size_t)b * CI * H * W;

    const int w16 = tid & 15, cipl = (tid >> 4) & 3, rest0 = tid >> 6;

    for (int kh = 0; kh < 3; ++kh) {
        const int gh = h - 1 + kh;
        __syncthreads();
        for (int it = 0; it < 18; ++it) {
            int rest = rest0 + it * 4;
            int whi = rest % 9, ciph = rest / 9;
            int w = whi * 16 + w16;
            int ci0 = (ciph * 4 + cipl) * 2;
            int gw = w - 1;
            float x0 = 0.0f, x1 = 0.0f;
            if (w < 130 && gw >= 0 && gw < W && gh >= 0 && gh < H) {
                const float* p = xb + (size_t)ci0 * (H * W) + gh * W + gw;
                x0 = p[0];
                x1 = p[H * W];
            }
            if (w < 130) {
                __hip_bfloat162 pk;
                pk.x = __float2bfloat16(x0);
                pk.y = __float2bfloat16(x1);
                *(__hip_bfloat162*)&xrow[w * XPAD + ci0] = pk;
            }
            float cs = x0 + x1;
            cs += __shfl_xor(cs, 16);
            cs += __shfl_xor(cs, 32);
            if (quad == 0 && w < 130) atomicAdd(&colsum[w], cs);
        }
        for (int kw = 0; kw < 3; ++kw) {
            __syncthreads();
            {
                const __hip_bfloat16* wtap = wt + (kh * 3 + kw) * (CO * CI);
#pragma unroll
                for (int it = 0; it < 4; ++it) {
                    int j = tid + it * 256;
                    int oc = j >> 3, ch = (j & 7) * 8;
                    short8 v = *(const short8*)(wtap + oc * CI + ch);
                    *(short8*)&wlds[oc * WPAD + ch] = v;
                }
            }
            __syncthreads();
#pragma unroll
            for (int kc = 0; kc < 2; ++kc) {
                const int krow = kc * 32 + quad * 8;
                short8 af[4], bf[4];
#pragma unroll
                for (int mi = 0; mi < 4; ++mi)
                    af[mi] = *(const short8*)&xrow[(m0 + mi * 16 + lo16 + kw) * XPAD + krow];
#pragma unroll
                for (int ni = 0; ni < 4; ++ni)
                    bf[ni] = *(const short8*)&wlds[(n0 + ni * 16 + lo16) * WPAD + krow];
#pragma unroll
                for (int mi = 0; mi < 4; ++mi)
#pragma unroll
                    for (int ni = 0; ni < 4; ++ni)
                        acc[mi][ni] = __builtin_amdgcn_mfma_f32_16x16x32_bf16(
                            af[mi], bf[ni], acc[mi][ni], 0, 0, 0);
            }
        }
    }
    __syncthreads();
#pragma unroll
    for (int mi = 0; mi < 4; ++mi) {
        const int wbase = m0 + mi * 16 + quad * 4;
        float cs[6];
#pragma unroll
        for (int r = 0; r < 6; ++r) cs[r] = colsum[wbase + r];
        float ps[4], cf[4];
#pragma unroll
        for (int r = 0; r < 4; ++r) {
            ps[r] = cs[r] + cs[r + 1] + cs[r + 2];
            cf[r] = B_COEF * (float)(h + wbase + r);
        }
#pragma unroll
        for (int ni = 0; ni < 4; ++ni) {
            const int oc = n0 + ni * 16 + lo16;
            const float bv = bias[oc];
            f32x4 v = acc[mi][ni];
#pragma unroll
            for (int r = 0; r < 4; ++r) v[r] = v[r] + cf[r] * ps[r] + bv;
            *(f32x4*)(out + (((size_t)b * CO + oc) * H + h) * W + wbase) = v;
        }
    }
}

// ===========================================================================

extern "C" void kernel_launch(void* const* d_in, const int* in_sizes, int n_in,
                              void* d_out, int out_size, void* d_ws, size_t ws_size,
                              hipStream_t stream) {
    const float* x    = (const float*)d_in[0];
    const float* wgt  = (const float*)d_in[1];
    const float* bias = (const float*)d_in[2];
    float* out = (float*)d_out;

    const size_t XT_BYTES = (size_t)16 * H * W * CI * 2;          // 33,554,432
    const size_t S_BYTES  = (size_t)16 * H * W * 4;               //  1,048,576
    const size_t WQ_BYTES = (size_t)9 * 2 * CO * 32 * 2 + 64;     //    147,520

    if (ws_size >= XT_BYTES + S_BYTES + WQ_BYTES) {
        __hip_bfloat16* xt = (__hip_bfloat16*)d_ws;
        float* S           = (float*)((char*)d_ws + XT_BYTES);
        __hip_bfloat16* wq = (__hip_bfloat16*)((char*)d_ws + XT_BYTES + S_BYTES);
        prep_x<<<dim3(H + 2, 16), dim3(256), 0, stream>>>(x, wgt, xt, S, wq);
        conv_main<<<dim3(2 * H, 16), dim3(256), 0, stream>>>(xt, wq, S, bias, out);
    } else {
        __hip_bfloat16* wt = (__hip_bfloat16*)d_ws;  // 147,456 B
        prep_w_fb<<<dim3(288), dim3(256), 0, stream>>>(wgt, wt);
        conv_fb<<<dim3(H, 16), dim3(256), 0, stream>>>(x, wt, bias, out);
    }
}

// Round 4
// 229.860 us; speedup vs baseline: 1.1221x; 1.0056x over previous
//
#include <hip/hip_runtime.h>
#include <hip/hip_bf16.h>

// PatchConv2d: out[b,o,h,w] = conv3x3(x,kernel) + 0.1*(h+w)*patch_sum[b,h,w] + bias[o]
// x:(16,64,128,128) f32, kernel:(128,64,3,3) f32, bias:(128,) f32 -> out(16,128,128,128) f32
//
// R7: FUSED single main kernel. The xt/S intermediate (33.5 MB write + ~100 MB
//     re-read + serialized launch) is gone. Each block = one output row h,
//     full W: loads 3 input rows straight from x NCHW with coalesced dword
//     loads (64 consec w / wave-instr), converts to bf16 in regs, ds_writes
//     short8 into XOR-swizzled NHWC LDS (write & read both bank-even),
//     accumulates channel sums for patch_sum inline. Then the proven 4-wave
//     full-W MFMA phase (B-frags straight from L2-resident wq).
//     LDS 51.4 KB -> 3 blocks/CU. Two cheap barriers, setprio around MFMA.

typedef __attribute__((ext_vector_type(8))) short short8;
typedef __attribute__((ext_vector_type(4))) float f32x4;

#define B_COEF 0.1f
constexpr int CI = 64, CO = 128, H = 128, W = 128;
constexpr int XPAD = 72;  // fallback-path LDS stride

static __device__ inline short bf16s(float v) {
    __hip_bfloat16 b = __float2bfloat16(v);
    return *reinterpret_cast<short*>(&b);
}

// ============================ fast path ====================================

// kernel f32 [oc][ci][3][3] -> bf16 wq[tap][kc][oc][32] (ci = kc*32+j)
__global__ void prep_wq(const float* __restrict__ wgt, __hip_bfloat16* __restrict__ wq) {
    int idx = blockIdx.x * 256 + threadIdx.x;  // 9*128*64 = 73728
    if (idx < 9 * CO * CI) {
        int tap = idx >> 13;
        int rem = idx & 8191;
        int oc = rem >> 6, ci = rem & 63;
        int kc = ci >> 5, j = ci & 31;
        wq[(((tap * 2 + kc) * CO + oc) << 5) + j] =
            __float2bfloat16(wgt[(oc * CI + ci) * 9 + tap]);
    }
}

// One output row (full W) per block: fused NCHW->NHWC-bf16 staging + conv.
__global__ __launch_bounds__(256, 3)
void conv_fused(const float* __restrict__ x,
                const __hip_bfloat16* __restrict__ wq,
                const float* __restrict__ bias,
                float* __restrict__ out) {
    __shared__ __hip_bfloat16 xrow[3][130 * 64];  // 49,920 B, swizzled units
    __shared__ float psum[256];
    __shared__ float ssumL[130];

    const int tid = threadIdx.x, bx = blockIdx.x, b = blockIdx.y;
    // XCD-coherent remap: xcd = bx&7 owns h in [xcd*16, xcd*16+16)
    const int h = ((bx & 7) << 4) | (bx >> 3);
    const int lane = tid & 63, waveid = tid >> 6;
    const int lo16 = lane & 15, quad = lane >> 4;
    const int m0 = (waveid & 1) * 64, n0 = (waveid >> 1) * 64;

    // ---- zero the two always-pad halo columns (slots 0 and 129)
    if (tid < 48) {
        const int r = tid >> 4, s = ((tid >> 3) & 1) ? 129 : 0, u = tid & 7;
        short8 z = {0, 0, 0, 0, 0, 0, 0, 0};
        *(short8*)&xrow[r][s * 64 + ((u ^ (s & 7)) * 8)] = z;
    }

    // ---- staged transpose: thread = (w, ci-group-half); 12 iters of
    //      {8 coalesced dword loads, cvt+pack, 1 swizzled ds_write_b128}
    const int wl = tid & 127, cg0 = tid >> 7;
    const int wslot = wl + 1, wsw = wslot & 7;
    float sacc = 0.0f;
    const float* xb = x + (size_t)b * CI * H * W + wl;
#pragma unroll
    for (int p = 0; p < 4; ++p) {
        const int cg = cg0 + 2 * p;
#pragma unroll
        for (int r = 0; r < 3; ++r) {
            const int gh = h - 1 + r;
            short8 pk = {0, 0, 0, 0, 0, 0, 0, 0};
            if (gh >= 0 && gh < H) {
                const float* px = xb + ((size_t)(cg * 8) * H + gh) * W;
                float v[8];
#pragma unroll
                for (int j = 0; j < 8; ++j) v[j] = px[(size_t)j * H * W];
#pragma unroll
                for (int j = 0; j < 8; ++j) {
                    pk[j] = bf16s(v[j]);
                    sacc += v[j];
                }
            }
            *(short8*)&xrow[r][wslot * 64 + ((cg ^ wsw) * 8)] = pk;
        }
    }
    psum[tid] = sacc;
    __syncthreads();

    // ---- column sums (patch_sum precursor, already 3-row summed)
    if (tid < 128) ssumL[tid + 1] = psum[tid] + psum[tid + 128];
    if (tid == 128) ssumL[0] = 0.0f;
    if (tid == 129) ssumL[129] = 0.0f;
    __syncthreads();

    // ---- MFMA phase (4 waves, 2x2 wave grid over W x OC)
    f32x4 acc[4][4] = {};

    __builtin_amdgcn_s_setprio(1);
#pragma unroll
    for (int kh = 0; kh < 3; ++kh) {
#pragma unroll
        for (int kw = 0; kw < 3; ++kw) {
            const int tap = kh * 3 + kw;
            // B-frags straight from L2-resident wq (1 KB coalesced per load)
            short8 bq[2][4];
#pragma unroll
            for (int kc = 0; kc < 2; ++kc)
#pragma unroll
                for (int ni = 0; ni < 4; ++ni)
                    bq[kc][ni] = *(const short8*)(
                        wq + (((tap * 2 + kc) * CO + n0 + ni * 16 + lo16) << 5) + quad * 8);
#pragma unroll
            for (int kc = 0; kc < 2; ++kc) {
                short8 af[4];
#pragma unroll
                for (int mi = 0; mi < 4; ++mi) {
                    const int row = m0 + mi * 16 + lo16 + kw;
                    af[mi] = *(const short8*)
                        &xrow[kh][row * 64 + (((kc * 4 + quad) ^ (row & 7)) * 8)];
                }
#pragma unroll
                for (int mi = 0; mi < 4; ++mi)
#pragma unroll
                    for (int ni = 0; ni < 4; ++ni)
                        acc[mi][ni] = __builtin_amdgcn_mfma_f32_16x16x32_bf16(
                            af[mi], bq[kc][ni], acc[mi][ni], 0, 0, 0);
            }
        }
    }
    __builtin_amdgcn_s_setprio(0);

    // ---- epilogue: + 0.1*(h+w)*patch_sum + bias; float4 stores
#pragma unroll
    for (int mi = 0; mi < 4; ++mi) {
        const int wbase = m0 + mi * 16 + quad * 4;
        float cs[6];
#pragma unroll
        for (int t = 0; t < 6; ++t) cs[t] = ssumL[wbase + t];
        float ps[4], cf[4];
#pragma unroll
        for (int t = 0; t < 4; ++t) {
            ps[t] = cs[t] + cs[t + 1] + cs[t + 2];
            cf[t] = B_COEF * (float)(h + wbase + t);
        }
#pragma unroll
        for (int ni = 0; ni < 4; ++ni) {
            const int oc = n0 + ni * 16 + lo16;
            const float bv = bias[oc];
            f32x4 v = acc[mi][ni];
#pragma unroll
            for (int t = 0; t < 4; ++t) v[t] = v[t] + cf[t] * ps[t] + bv;
            *(f32x4*)(out + (((size_t)b * CO + oc) * H + h) * W + wbase) = v;
        }
    }
}

// ===================== fallback path (R2, needs only 147 KB ws) ============

constexpr int WPAD = 72;

__global__ void prep_w_fb(const float* __restrict__ wgt, __hip_bfloat16* __restrict__ wt) {
    int idx = blockIdx.x * 256 + threadIdx.x;
    if (idx < 9 * CO * CI) {
        int tap = idx / (CO * CI);
        int rem = idx - tap * (CO * CI);
        int oc = rem >> 6, ci = rem & 63;
        wt[idx] = __float2bfloat16(wgt[(oc * CI + ci) * 9 + tap]);
    }
}

__global__ __launch_bounds__(256, 2)
void conv_fb(const float* __restrict__ x, const __hip_bfloat16* __restrict__ wt,
             const float* __restrict__ bias, float* __restrict__ out) {
    __shared__ __hip_bfloat16 xrow[130 * XPAD];
    __shared__ __hip_bfloat16 wlds[CO * WPAD];
    __shared__ float colsum[132];

    const int tid = threadIdx.x;
    const int h = blockIdx.x, b = blockIdx.y;
    const int lane = tid & 63, waveid = tid >> 6;
    const int lo16 = lane & 15, quad = lane >> 4;
    const int m0 = (waveid & 1) * 64, n0 = (waveid >> 1) * 64;

    f32x4 acc[4][4] = {};
    if (tid < 132) colsum[tid] = 0.0f;
    const float* xb = x + (size_t)b * CI * H * W;

    const int w16 = tid & 15, cipl = (tid >> 4) & 3, rest0 = tid >> 6;

    for (int kh = 0; kh < 3; ++kh) {
        const int gh = h - 1 + kh;
        __syncthreads();
        for (int it = 0; it < 18; ++it) {
            int rest = rest0 + it * 4;
            int whi = rest % 9, ciph = rest / 9;
            int w = whi * 16 + w16;
            int ci0 = (ciph * 4 + cipl) * 2;
            int gw = w - 1;
            float x0 = 0.0f, x1 = 0.0f;
            if (w < 130 && gw >= 0 && gw < W && gh >= 0 && gh < H) {
                const float* p = xb + (size_t)ci0 * (H * W) + gh * W + gw;
                x0 = p[0];
                x1 = p[H * W];
            }
            if (w < 130) {
                __hip_bfloat162 pk;
                pk.x = __float2bfloat16(x0);
                pk.y = __float2bfloat16(x1);
                *(__hip_bfloat162*)&xrow[w * XPAD + ci0] = pk;
            }
            float cs = x0 + x1;
            cs += __shfl_xor(cs, 16);
            cs += __shfl_xor(cs, 32);
            if (quad == 0 && w < 130) atomicAdd(&colsum[w], cs);
        }
        for (int kw = 0; kw < 3; ++kw) {
            __syncthreads();
            {
                const __hip_bfloat16* wtap = wt + (kh * 3 + kw) * (CO * CI);
#pragma unroll
                for (int it = 0; it < 4; ++it) {
                    int j = tid + it * 256;
                    int oc = j >> 3, ch = (j & 7) * 8;
                    short8 v = *(const short8*)(wtap + oc * CI + ch);
                    *(short8*)&wlds[oc * WPAD + ch] = v;
                }
            }
            __syncthreads();
#pragma unroll
            for (int kc = 0; kc < 2; ++kc) {
                const int krow = kc * 32 + quad * 8;
                short8 af[4], bf[4];
#pragma unroll
                for (int mi = 0; mi < 4; ++mi)
                    af[mi] = *(const short8*)&xrow[(m0 + mi * 16 + lo16 + kw) * XPAD + krow];
#pragma unroll
                for (int ni = 0; ni < 4; ++ni)
                    bf[ni] = *(const short8*)&wlds[(n0 + ni * 16 + lo16) * WPAD + krow];
#pragma unroll
                for (int mi = 0; mi < 4; ++mi)
#pragma unroll
                    for (int ni = 0; ni < 4; ++ni)
                        acc[mi][ni] = __builtin_amdgcn_mfma_f32_16x16x32_bf16(
                            af[mi], bf[ni], acc[mi][ni], 0, 0, 0);
            }
        }
    }
    __syncthreads();
#pragma unroll
    for (int mi = 0; mi < 4; ++mi) {
        const int wbase = m0 + mi * 16 + quad * 4;
        float cs[6];
#pragma unroll
        for (int r = 0; r < 6; ++r) cs[r] = colsum[wbase + r];
        float ps[4], cf[4];
#pragma unroll
        for (int r = 0; r < 4; ++r) {
            ps[r] = cs[r] + cs[r + 1] + cs[r + 2];
            cf[r] = B_COEF * (float)(h + wbase + r);
        }
#pragma unroll
        for (int ni = 0; ni < 4; ++ni) {
            const int oc = n0 + ni * 16 + lo16;
            const float bv = bias[oc];
            f32x4 v = acc[mi][ni];
#pragma unroll
            for (int r = 0; r < 4; ++r) v[r] = v[r] + cf[r] * ps[r] + bv;
            *(f32x4*)(out + (((size_t)b * CO + oc) * H + h) * W + wbase) = v;
        }
    }
}

// ===========================================================================

extern "C" void kernel_launch(void* const* d_in, const int* in_sizes, int n_in,
                              void* d_out, int out_size, void* d_ws, size_t ws_size,
                              hipStream_t stream) {
    const float* x    = (const float*)d_in[0];
    const float* wgt  = (const float*)d_in[1];
    const float* bias = (const float*)d_in[2];
    float* out = (float*)d_out;

    const size_t WQ_BYTES = (size_t)9 * 2 * CO * 32 * 2;  // 147,456

    if (ws_size >= WQ_BYTES) {
        __hip_bfloat16* wq = (__hip_bfloat16*)d_ws;
        prep_wq<<<dim3(288), dim3(256), 0, stream>>>(wgt, wq);
        conv_fused<<<dim3(H, 16), dim3(256), 0, stream>>>(x, wq, bias, out);
    } else {
        __hip_bfloat16* wt = (__hip_bfloat16*)d_ws;  // 147,456 B
        prep_w_fb<<<dim3(288), dim3(256), 0, stream>>>(wgt, wt);
        conv_fb<<<dim3(H, 16), dim3(256), 0, stream>>>(x, wt, bias, out);
    }
}